// Round 2
// baseline (446.937 us; speedup 1.0000x reference)
//
#include <hip/hip_runtime.h>
#include <hip/hip_bf16.h>

#define DD 256
#define NGN 80000
#define NMN 20000
#define NEE 160000

typedef unsigned short u16;
typedef __attribute__((ext_vector_type(8))) short s16x8;
typedef __attribute__((ext_vector_type(4))) short s16x4;
typedef __attribute__((ext_vector_type(4))) float f32x4;

__device__ __forceinline__ u16 f2bf(float f) {
  union { float f; unsigned u; } v; v.f = f;
  unsigned r = (v.u + 0x7FFFu + ((v.u >> 16) & 1u)) >> 16;
  return (u16)r;
}
__device__ __forceinline__ float bf2f(u16 x) {
  union { unsigned u; float f; } v; v.u = ((unsigned)x) << 16;
  return v.f;
}

// Pack fp32 weight [K][256] -> bf16 fragment-linear layout [kt][nt][lane][8]
// slot->k bijection: k = kt*32 + 4*(lane>>4) + (i<4 ? i : 12+i); n = nt*16 + (lane&15)
__global__ void pack_weights(const float* __restrict__ W, u16* __restrict__ dst, int K) {
  int idx = blockIdx.x * 256 + threadIdx.x;
  if (idx >= K * 256) return;
  int i = idx & 7;
  int lane = (idx >> 3) & 63;
  int nt = (idx >> 9) & 15;
  int kt = idx >> 13;
  int k = kt * 32 + 4 * (lane >> 4) + (i < 4 ? i : 12 + i);
  int n = nt * 16 + (lane & 15);
  dst[idx] = f2bf(W[(size_t)k * 256 + n]);
}

__device__ __forceinline__ void stage16k(const u16* __restrict__ gsrc, u16* lds, int tid) {
  const s16x8* s = (const s16x8*)gsrc;
  s16x8* d = (s16x8*)lds;
#pragma unroll
  for (int j = 0; j < 4; ++j) d[tid + 256 * j] = s[tid + 256 * j];
}

// Dense GEMM: Y(bf16)[n][256] = X(fp32)[n][256] @ Wp(packed 8 slabs)
__global__ __launch_bounds__(256, 2) void gemm_ns(
    const float* __restrict__ X, const u16* __restrict__ Wp,
    u16* __restrict__ Y, int n) {
  __shared__ u16 bstage[8192];
  __shared__ u16 ob[16384];
  const int tid = threadIdx.x;
  const int lane = tid & 63;
  const int wave = tid >> 6;
  const int mr = wave >> 1, nc = wave & 1;
  const int g = lane >> 4, lr = lane & 15;
  const int row0 = blockIdx.x * 64;

  const float* pX[2];
#pragma unroll
  for (int mt = 0; mt < 2; ++mt) {
    int r = min(row0 + mr * 32 + mt * 16 + lr, n - 1);
    pX[mt] = X + (size_t)r * DD;
  }
  const f32x4 fz = {0.f, 0.f, 0.f, 0.f};
  f32x4 acc[2][8];
#pragma unroll
  for (int mt = 0; mt < 2; ++mt)
#pragma unroll
    for (int nt = 0; nt < 8; ++nt) acc[mt][nt] = fz;

  for (int kl = 0; kl < 8; ++kl) {
    __syncthreads();
    stage16k(Wp + (size_t)kl * 8192, bstage, tid);
    __syncthreads();
    s16x8 afr[2];
    const int c0 = kl * 32 + 4 * g;
#pragma unroll
    for (int mt = 0; mt < 2; ++mt) {
      f32x4 f0 = *(const f32x4*)(pX[mt] + c0);
      f32x4 f1 = *(const f32x4*)(pX[mt] + c0 + 16);
      s16x8 a;
#pragma unroll
      for (int j = 0; j < 4; ++j) {
        a[j] = (short)f2bf(f0[j]);
        a[4 + j] = (short)f2bf(f1[j]);
      }
      afr[mt] = a;
    }
#pragma unroll
    for (int nt = 0; nt < 8; ++nt) {
      s16x8 b = *(const s16x8*)(bstage + ((size_t)(nc * 8 + nt) * 64 + lane) * 8);
      acc[0][nt] = __builtin_amdgcn_mfma_f32_16x16x32_bf16(afr[0], b, acc[0][nt], 0, 0, 0);
      acc[1][nt] = __builtin_amdgcn_mfma_f32_16x16x32_bf16(afr[1], b, acc[1][nt], 0, 0, 0);
    }
  }
  // stage to LDS (swizzled) then coalesced store
#pragma unroll
  for (int mt = 0; mt < 2; ++mt)
#pragma unroll
    for (int nt = 0; nt < 8; ++nt)
#pragma unroll
      for (int i = 0; i < 4; ++i) {
        int rowL = mr * 32 + mt * 16 + 4 * g + i;
        int col = nc * 128 + nt * 16 + lr;
        int byte = rowL * 512 + ((col * 2) ^ ((rowL & 7) << 4));
        *(u16*)((char*)ob + byte) = f2bf(acc[mt][nt][i]);
      }
  __syncthreads();
#pragma unroll
  for (int rr = 0; rr < 16; ++rr) {
    int rowL = wave * 16 + rr;
    int rg = row0 + rowL;
    if (rg < n) {
      s16x4 v = *(const s16x4*)((char*)ob + rowL * 512 + ((lane * 8) ^ ((rowL & 7) << 4)));
      *(s16x4*)(Y + (size_t)rg * DD + lane * 4) = v;
    }
  }
}

// Edge kernel: acc = GS[src]+GM[dst] (C-init) ; += efeat@W1e ; SiLU ; @W2 ; LN ; atomic scatter
__global__ __launch_bounds__(256, 2) void edge_fused(
    const float* __restrict__ efeat,
    const u16* __restrict__ GSp, const u16* __restrict__ GMp,
    const int* __restrict__ sidx, const int* __restrict__ didx,
    const u16* __restrict__ W1p, const float* __restrict__ b1,
    const u16* __restrict__ W2p, const float* __restrict__ b2,
    const float* __restrict__ gam, const float* __restrict__ bet,
    float* __restrict__ agg) {
  __shared__ u16 uni[16384];     // 32 KB: gsm, then hbuf
  __shared__ u16 bstage[8192];   // 16 KB weight slab
  __shared__ float2 pstats[64][2];

  const int tid = threadIdx.x;
  const int lane = tid & 63;
  const int wave = tid >> 6;
  const int mr = wave >> 1, nc = wave & 1;
  const int g = lane >> 4, lr = lane & 15;
  const int row0 = blockIdx.x * 64;

  // Phase 1: gather GS[src]+GM[dst] -> uni (bf16, XOR-swizzled rows). 2 rows/instr.
#pragma unroll
  for (int j = 0; j < 8; ++j) {
    int e = wave * 16 + j * 2 + (lane >> 5);
    int rg = row0 + e;
    int rs = sidx[rg], rd = didx[rg];
    int co = (lane & 31) * 8;  // u16 col offset within row
    s16x8 a = *(const s16x8*)(GSp + (size_t)rs * DD + co);
    s16x8 b = *(const s16x8*)(GMp + (size_t)rd * DD + co);
    s16x8 o;
#pragma unroll
    for (int k2 = 0; k2 < 8; ++k2)
      o[k2] = (short)f2bf(bf2f((u16)a[k2]) + bf2f((u16)b[k2]));
    int byte = e * 512 + ((co * 2) ^ ((e & 7) << 4));
    *(s16x8*)((char*)uni + byte) = o;
  }
  __syncthreads();

  // Phase 2: C-init accumulators from uni
  f32x4 acc[2][8];
#pragma unroll
  for (int mt = 0; mt < 2; ++mt)
#pragma unroll
    for (int nt = 0; nt < 8; ++nt)
#pragma unroll
      for (int i = 0; i < 4; ++i) {
        int rowL = mr * 32 + mt * 16 + 4 * g + i;
        int col = nc * 128 + nt * 16 + lr;
        int byte = rowL * 512 + ((col * 2) ^ ((rowL & 7) << 4));
        acc[mt][nt][i] = bf2f(*(const u16*)((char*)uni + byte));
      }

  // Phase 3: GEMM1 over K=256 (efeat only)
  const float* pe[2];
#pragma unroll
  for (int mt = 0; mt < 2; ++mt)
    pe[mt] = efeat + (size_t)(row0 + mr * 32 + mt * 16 + lr) * DD;

  for (int kl = 0; kl < 8; ++kl) {
    __syncthreads();
    stage16k(W1p + (size_t)kl * 8192, bstage, tid);
    __syncthreads();
    s16x8 afr[2];
    const int c0 = kl * 32 + 4 * g;
#pragma unroll
    for (int mt = 0; mt < 2; ++mt) {
      f32x4 f0 = *(const f32x4*)(pe[mt] + c0);
      f32x4 f1 = *(const f32x4*)(pe[mt] + c0 + 16);
      s16x8 a;
#pragma unroll
      for (int j = 0; j < 4; ++j) {
        a[j] = (short)f2bf(f0[j]);
        a[4 + j] = (short)f2bf(f1[j]);
      }
      afr[mt] = a;
    }
#pragma unroll
    for (int nt = 0; nt < 8; ++nt) {
      s16x8 b = *(const s16x8*)(bstage + ((size_t)(nc * 8 + nt) * 64 + lane) * 8);
      acc[0][nt] = __builtin_amdgcn_mfma_f32_16x16x32_bf16(afr[0], b, acc[0][nt], 0, 0, 0);
      acc[1][nt] = __builtin_amdgcn_mfma_f32_16x16x32_bf16(afr[1], b, acc[1][nt], 0, 0, 0);
    }
  }

  // Phase 4: bias1 + SiLU -> uni (hbuf, swizzled)
  {
    float b1v[8];
#pragma unroll
    for (int nt = 0; nt < 8; ++nt) b1v[nt] = b1[nc * 128 + nt * 16 + lr];
#pragma unroll
    for (int mt = 0; mt < 2; ++mt)
#pragma unroll
      for (int nt = 0; nt < 8; ++nt)
#pragma unroll
        for (int i = 0; i < 4; ++i) {
          float x = acc[mt][nt][i] + b1v[nt];
          float h = x / (1.f + __expf(-x));
          int rowL = mr * 32 + mt * 16 + 4 * g + i;
          int col = nc * 128 + nt * 16 + lr;
          int byte = rowL * 512 + ((col * 2) ^ ((rowL & 7) << 4));
          *(u16*)((char*)uni + byte) = f2bf(h);
        }
  }

  // Phase 5: GEMM2 h @ W2
  f32x4 acc2[2][8];
  const f32x4 fz = {0.f, 0.f, 0.f, 0.f};
#pragma unroll
  for (int mt = 0; mt < 2; ++mt)
#pragma unroll
    for (int nt = 0; nt < 8; ++nt) acc2[mt][nt] = fz;

  for (int kt2 = 0; kt2 < 8; ++kt2) {
    __syncthreads();
    stage16k(W2p + (size_t)kt2 * 8192, bstage, tid);
    __syncthreads();
    s16x8 afr[2];
#pragma unroll
    for (int mt = 0; mt < 2; ++mt) {
      int rowL = mr * 32 + mt * 16 + lr;
      int swz = (rowL & 7) << 4;
      int cL = kt2 * 32 + 4 * g;
      s16x4 lo = *(const s16x4*)((char*)uni + rowL * 512 + ((cL * 2) ^ swz));
      s16x4 hi = *(const s16x4*)((char*)uni + rowL * 512 + (((cL + 16) * 2) ^ swz));
      s16x8 a;
#pragma unroll
      for (int j = 0; j < 4; ++j) {
        a[j] = lo[j];
        a[4 + j] = hi[j];
      }
      afr[mt] = a;
    }
#pragma unroll
    for (int nt = 0; nt < 8; ++nt) {
      s16x8 b = *(const s16x8*)(bstage + ((size_t)(nc * 8 + nt) * 64 + lane) * 8);
      acc2[0][nt] = __builtin_amdgcn_mfma_f32_16x16x32_bf16(afr[0], b, acc2[0][nt], 0, 0, 0);
      acc2[1][nt] = __builtin_amdgcn_mfma_f32_16x16x32_bf16(afr[1], b, acc2[1][nt], 0, 0, 0);
    }
  }

  // Phase 6: bias2 + LayerNorm + atomic scatter to agg
  float b2v[8], gv[8], bv[8];
#pragma unroll
  for (int nt = 0; nt < 8; ++nt) {
    int col = nc * 128 + nt * 16 + lr;
    b2v[nt] = b2[col];
    gv[nt] = gam[col];
    bv[nt] = bet[col];
  }
#pragma unroll
  for (int mt = 0; mt < 2; ++mt)
#pragma unroll
    for (int i = 0; i < 4; ++i) {
      float s = 0.f, s2 = 0.f;
#pragma unroll
      for (int nt = 0; nt < 8; ++nt) {
        float y = acc2[mt][nt][i] + b2v[nt];
        s += y;
        s2 += y * y;
      }
#pragma unroll
      for (int m = 1; m < 16; m <<= 1) {
        s += __shfl_xor(s, m);
        s2 += __shfl_xor(s2, m);
      }
      if (lr == 0) pstats[mr * 32 + mt * 16 + 4 * g + i][nc] = make_float2(s, s2);
    }
  __syncthreads();
#pragma unroll
  for (int mt = 0; mt < 2; ++mt)
#pragma unroll
    for (int i = 0; i < 4; ++i) {
      int rowL = mr * 32 + mt * 16 + 4 * g + i;
      float2 pa = pstats[rowL][0], pb = pstats[rowL][1];
      float sum = pa.x + pb.x, sq = pa.y + pb.y;
      float mu = sum * (1.f / 256.f);
      float var = fmaxf(sq * (1.f / 256.f) - mu * mu, 0.f);
      float rs = rsqrtf(var + 1e-5f);
      int rg = row0 + rowL;
      int dn = didx[rg];
#pragma unroll
      for (int nt = 0; nt < 8; ++nt) {
        int col = nc * 128 + nt * 16 + lr;
        float y = acc2[mt][nt][i] + b2v[nt];
        float val = (y - mu) * rs * gv[nt] + bv[nt];
        atomicAdd(agg + (size_t)dn * DD + col, val);
      }
    }
}

// MODE 1: src/grid MLP (K1=256) -> residual write
// MODE 2: dst/mesh MLP (concat[agg|mesh], K1=512) -> residual write
template <int MODE, int K1>
__global__ __launch_bounds__(256, 2) void mlp_fused(
    const float* __restrict__ xa, const float* __restrict__ xb,
    const u16* __restrict__ W1p, const float* __restrict__ b1,
    const u16* __restrict__ W2p, const float* __restrict__ b2,
    const float* __restrict__ gam, const float* __restrict__ bet,
    const float* __restrict__ resid, float* __restrict__ out, int nrows) {
  __shared__ u16 bstage[8192];
  __shared__ u16 hbuf[64 * 256];
  __shared__ float2 pstats[64][2];

  const int tid = threadIdx.x;
  const int lane = tid & 63;
  const int wave = tid >> 6;
  const int mr = wave >> 1, nc = wave & 1;
  const int g = lane >> 4, lr = lane & 15;
  const int row0 = blockIdx.x * 64;

  const float* pA[2][2];
#pragma unroll
  for (int mt = 0; mt < 2; ++mt) {
    int r = row0 + mr * 32 + mt * 16 + lr;
    if (MODE == 2) r = min(r, nrows - 1);
    pA[mt][0] = xa + (size_t)r * DD;
    if constexpr (MODE == 2) pA[mt][1] = xb + (size_t)r * DD;
  }

  const f32x4 fz = {0.f, 0.f, 0.f, 0.f};
  f32x4 acc[2][8];
#pragma unroll
  for (int mt = 0; mt < 2; ++mt)
#pragma unroll
    for (int nt = 0; nt < 8; ++nt) acc[mt][nt] = fz;

#pragma unroll
  for (int region = 0; region < K1 / 256; ++region) {
    for (int kl = 0; kl < 8; ++kl) {
      const int kt = region * 8 + kl;
      __syncthreads();
      stage16k(W1p + (size_t)kt * 8192, bstage, tid);
      __syncthreads();
      s16x8 afr[2];
      const int c0 = kl * 32 + 4 * g;
#pragma unroll
      for (int mt = 0; mt < 2; ++mt) {
        const float* p = pA[mt][region] + c0;
        f32x4 f0 = *(const f32x4*)p;
        f32x4 f1 = *(const f32x4*)(p + 16);
        s16x8 a;
#pragma unroll
        for (int j = 0; j < 4; ++j) {
          a[j] = (short)f2bf(f0[j]);
          a[4 + j] = (short)f2bf(f1[j]);
        }
        afr[mt] = a;
      }
#pragma unroll
      for (int nt = 0; nt < 8; ++nt) {
        s16x8 b = *(const s16x8*)(bstage + ((size_t)(nc * 8 + nt) * 64 + lane) * 8);
        acc[0][nt] = __builtin_amdgcn_mfma_f32_16x16x32_bf16(afr[0], b, acc[0][nt], 0, 0, 0);
        acc[1][nt] = __builtin_amdgcn_mfma_f32_16x16x32_bf16(afr[1], b, acc[1][nt], 0, 0, 0);
      }
    }
  }

  {
    float b1v[8];
#pragma unroll
    for (int nt = 0; nt < 8; ++nt) b1v[nt] = b1[nc * 128 + nt * 16 + lr];
#pragma unroll
    for (int mt = 0; mt < 2; ++mt)
#pragma unroll
      for (int nt = 0; nt < 8; ++nt)
#pragma unroll
        for (int i = 0; i < 4; ++i) {
          float x = acc[mt][nt][i] + b1v[nt];
          float h = x / (1.f + __expf(-x));
          int rowL = mr * 32 + mt * 16 + 4 * g + i;
          int col = nc * 128 + nt * 16 + lr;
          int byte = rowL * 512 + ((col * 2) ^ ((rowL & 7) << 4));
          *(u16*)((char*)hbuf + byte) = f2bf(h);
        }
  }

  f32x4 acc2[2][8];
#pragma unroll
  for (int mt = 0; mt < 2; ++mt)
#pragma unroll
    for (int nt = 0; nt < 8; ++nt) acc2[mt][nt] = fz;

  for (int kt2 = 0; kt2 < 8; ++kt2) {
    __syncthreads();
    stage16k(W2p + (size_t)kt2 * 8192, bstage, tid);
    __syncthreads();
    s16x8 afr[2];
#pragma unroll
    for (int mt = 0; mt < 2; ++mt) {
      int rowL = mr * 32 + mt * 16 + lr;
      int swz = (rowL & 7) << 4;
      int cL = kt2 * 32 + 4 * g;
      s16x4 lo = *(const s16x4*)((char*)hbuf + rowL * 512 + ((cL * 2) ^ swz));
      s16x4 hi = *(const s16x4*)((char*)hbuf + rowL * 512 + (((cL + 16) * 2) ^ swz));
      s16x8 a;
#pragma unroll
      for (int j = 0; j < 4; ++j) {
        a[j] = lo[j];
        a[4 + j] = hi[j];
      }
      afr[mt] = a;
    }
#pragma unroll
    for (int nt = 0; nt < 8; ++nt) {
      s16x8 b = *(const s16x8*)(bstage + ((size_t)(nc * 8 + nt) * 64 + lane) * 8);
      acc2[0][nt] = __builtin_amdgcn_mfma_f32_16x16x32_bf16(afr[0], b, acc2[0][nt], 0, 0, 0);
      acc2[1][nt] = __builtin_amdgcn_mfma_f32_16x16x32_bf16(afr[1], b, acc2[1][nt], 0, 0, 0);
    }
  }

  float b2v[8], gv[8], bv[8];
#pragma unroll
  for (int nt = 0; nt < 8; ++nt) {
    int col = nc * 128 + nt * 16 + lr;
    b2v[nt] = b2[col];
    gv[nt] = gam[col];
    bv[nt] = bet[col];
  }
#pragma unroll
  for (int mt = 0; mt < 2; ++mt)
#pragma unroll
    for (int i = 0; i < 4; ++i) {
      float s = 0.f, s2 = 0.f;
#pragma unroll
      for (int nt = 0; nt < 8; ++nt) {
        float y = acc2[mt][nt][i] + b2v[nt];
        s += y;
        s2 += y * y;
      }
#pragma unroll
      for (int m = 1; m < 16; m <<= 1) {
        s += __shfl_xor(s, m);
        s2 += __shfl_xor(s2, m);
      }
      if (lr == 0) pstats[mr * 32 + mt * 16 + 4 * g + i][nc] = make_float2(s, s2);
    }
  __syncthreads();
#pragma unroll
  for (int mt = 0; mt < 2; ++mt)
#pragma unroll
    for (int i = 0; i < 4; ++i) {
      int rowL = mr * 32 + mt * 16 + 4 * g + i;
      float2 pa = pstats[rowL][0], pb = pstats[rowL][1];
      float sum = pa.x + pb.x, sq = pa.y + pb.y;
      float mu = sum * (1.f / 256.f);
      float var = fmaxf(sq * (1.f / 256.f) - mu * mu, 0.f);
      float rs = rsqrtf(var + 1e-5f);
      int rg = row0 + rowL;
      if (MODE == 2 && rg >= nrows) continue;
#pragma unroll
      for (int nt = 0; nt < 8; ++nt) {
        int col = nc * 128 + nt * 16 + lr;
        float y = acc2[mt][nt][i] + b2v[nt];
        float val = (y - mu) * rs * gv[nt] + bv[nt];
        out[(size_t)rg * DD + col] = resid[(size_t)rg * DD + col] + val;
      }
    }
}

extern "C" void kernel_launch(void* const* d_in, const int* in_sizes, int n_in,
                              void* d_out, int out_size, void* d_ws, size_t ws_size,
                              hipStream_t stream) {
  const float* g2m  = (const float*)d_in[0];
  const float* grid = (const float*)d_in[1];
  const float* mesh = (const float*)d_in[2];
  const int* sidx = (const int*)d_in[3];
  const int* didx = (const int*)d_in[4];
  const float* eW1 = (const float*)d_in[5];
  const float* eb1 = (const float*)d_in[6];
  const float* eW2 = (const float*)d_in[7];
  const float* eb2 = (const float*)d_in[8];
  const float* eg  = (const float*)d_in[9];
  const float* ebt = (const float*)d_in[10];
  const float* sW1 = (const float*)d_in[11];
  const float* sb1 = (const float*)d_in[12];
  const float* sW2 = (const float*)d_in[13];
  const float* sb2 = (const float*)d_in[14];
  const float* sg  = (const float*)d_in[15];
  const float* sbt = (const float*)d_in[16];
  const float* dW1 = (const float*)d_in[17];
  const float* db1 = (const float*)d_in[18];
  const float* dW2 = (const float*)d_in[19];
  const float* db2 = (const float*)d_in[20];
  const float* dg  = (const float*)d_in[21];
  const float* dbt = (const float*)d_in[22];

  float* agg = (float*)d_ws;  // [NMN][256] fp32
  u16* wp = (u16*)((char*)d_ws + (size_t)NMN * DD * 4);
  u16* eW1p = wp;                       // 768 rows: slabs 0-7 efeat, 8-15 src, 16-23 dst
  u16* eW2p = eW1p + 768 * 256;
  u16* sW1p = eW2p + 256 * 256;
  u16* sW2p = sW1p + 256 * 256;
  u16* dW1p = sW2p + 256 * 256;
  u16* dW2p = dW1p + 512 * 256;

  float* gout = (float*)d_out;
  float* mout = gout + (size_t)NGN * DD;
  // GS/GM scratch inside the grid-output half of d_out (overwritten last by MODE1)
  u16* GSp = (u16*)d_out;                  // 40.96 MB
  u16* GMp = GSp + (size_t)NGN * DD;       // 10.24 MB (ends at 51.2 MB < 81.92 MB)

  (void)hipMemsetAsync(agg, 0, (size_t)NMN * DD * 4, stream);
  pack_weights<<<768, 256, 0, stream>>>(eW1, eW1p, 768);
  pack_weights<<<256, 256, 0, stream>>>(eW2, eW2p, 256);
  pack_weights<<<256, 256, 0, stream>>>(sW1, sW1p, 256);
  pack_weights<<<256, 256, 0, stream>>>(sW2, sW2p, 256);
  pack_weights<<<512, 256, 0, stream>>>(dW1, dW1p, 512);
  pack_weights<<<256, 256, 0, stream>>>(dW2, dW2p, 256);

  // Node-contribution tables: GS = grid @ eW1[256:512], GM = mesh @ eW1[512:768]
  gemm_ns<<<NGN / 64, 256, 0, stream>>>(grid, eW1p + 8 * 8192, GSp, NGN);
  gemm_ns<<<(NMN + 63) / 64, 256, 0, stream>>>(mesh, eW1p + 16 * 8192, GMp, NMN);

  edge_fused<<<NEE / 64, 256, 0, stream>>>(
      g2m, GSp, GMp, sidx, didx, eW1p, eb1, eW2p, eb2, eg, ebt, agg);

  mlp_fused<2, 512><<<(NMN + 63) / 64, 256, 0, stream>>>(
      agg, mesh, dW1p, db1, dW2p, db2, dg, dbt, mesh, mout, NMN);
  mlp_fused<1, 256><<<NGN / 64, 256, 0, stream>>>(
      grid, nullptr, sW1p, sb1, sW2p, sb2, sg, sbt, grid, gout, NGN);
}